// Round 1
// baseline (587.783 us; speedup 1.0000x reference)
//
#include <hip/hip_runtime.h>

// Bilinear per-image shift with mirror boundary.
// images: (256, 512, 512, 1) fp32; dxdy: (256, 2) fp32 -> (dy, dx) per image.
// out:    (256, 512, 512) fp32.
// Memory-bound: 512 MB min traffic -> ~81 us roofline at 6.3 TB/s.

__device__ __forceinline__ int mirror_idx(int idx, int n) {
    const int p = 2 * (n - 1);
    int i = abs(idx) % p;          // compiler emits magic-mul for % 1022
    return (i >= n) ? (p - i) : i;
}

__global__ __launch_bounds__(256) void shift_bilinear_kernel(
    const float* __restrict__ images,
    const float* __restrict__ dxdy,
    float* __restrict__ out)
{
    constexpr int H = 512, W = 512;
    constexpr int HW = H * W;                 // 2^18

    // Each thread produces 4 consecutive x-pixels (float4 store).
    const long long tid = (long long)blockIdx.x * blockDim.x + threadIdx.x;
    const long long pix = tid * 4;
    const int b   = (int)(pix >> 18);         // / (512*512)
    const int rem = (int)(pix & (HW - 1));
    const int y   = rem >> 9;                 // / 512
    const int x   = rem & (W - 1);

    // Per-image shift (uniform within a block: 1024 px/block, HW % 1024 == 0).
    const float dy = dxdy[2 * b + 0];
    const float dx = dxdy[2 * b + 1];

    // Row math (uniform across the 4 pixels).
    const float cy  = (float)y - dy;
    const float y0f = floorf(cy);
    const float fy  = cy - y0f;
    const int   y0  = (int)y0f;               // y0f integral -> exact
    const int  y0m  = mirror_idx(y0,     H);
    const int  y1m  = mirror_idx(y0 + 1, H);

    const float* __restrict__ row0 = images + ((long long)b * H + y0m) * W;
    const float* __restrict__ row1 = images + ((long long)b * H + y1m) * W;

    float res[4];
#pragma unroll
    for (int j = 0; j < 4; ++j) {
        const int   xj  = x + j;
        // Match reference fp32 ops exactly: per-pixel floor, not hoisted frac.
        const float cx  = (float)xj - dx;
        const float x0f = floorf(cx);
        const float fx  = cx - x0f;
        const int   x0  = (int)x0f;
        const int  x0m  = mirror_idx(x0,     W);
        const int  x1m  = mirror_idx(x0 + 1, W);

        const float v00 = row0[x0m];
        const float v01 = row0[x1m];
        const float v10 = row1[x0m];
        const float v11 = row1[x1m];

        res[j] = (1.0f - fy) * ((1.0f - fx) * v00 + fx * v01)
               +         fy  * ((1.0f - fx) * v10 + fx * v11);
    }

    *reinterpret_cast<float4*>(out + pix) =
        make_float4(res[0], res[1], res[2], res[3]);
}

extern "C" void kernel_launch(void* const* d_in, const int* in_sizes, int n_in,
                              void* d_out, int out_size, void* d_ws, size_t ws_size,
                              hipStream_t stream) {
    const float* images = (const float*)d_in[0];
    const float* dxdy   = (const float*)d_in[1];
    float*       out    = (float*)d_out;

    // out_size = 256*512*512 = 2^26 pixels; 4 px/thread; 256 thr/block.
    const long long n_threads = (long long)out_size / 4;
    const int blocks = (int)((n_threads + 255) / 256);
    shift_bilinear_kernel<<<blocks, 256, 0, stream>>>(images, dxdy, out);
}

// Round 2
// 433.275 us; speedup vs baseline: 1.3566x; 1.3566x over previous
//
#include <hip/hip_runtime.h>

// Bilinear per-image shift with mirror boundary — uniform-shift formulation.
//
// Since dx,dy are constant per image and x,y are integers:
//   floor(x - dx) = x + floor(-dx),  frac(x - dx) = frac(-dx)   (to ~ulp)
// so the op is a constant integer shift + constant 4-tap blend per image.
// Interior pixels need 5 consecutive source columns from 2 source rows ->
// two aligned float4 loads per row + wave-uniform window select.
//
// Traffic: ~196 MB fetch (L2 absorbs row reuse) + 256 MB write -> ~75 us
// roofline at 6.3 TB/s.

__device__ __forceinline__ int mirror_small(int v) {
    // Reflect into [0,511]; valid for v in [-1022, 1533] (single reflection).
    v = abs(v);
    return (v > 511) ? (1022 - v) : v;
}

__device__ __forceinline__ float4 blend5(
    float u0, float u1, float u2, float u3, float u4,
    float v0, float v1, float v2, float v3, float v4,
    float w00, float w01, float w10, float w11)
{
    float4 r;
    r.x = w00 * u0 + w01 * u1 + w10 * v0 + w11 * v1;
    r.y = w00 * u1 + w01 * u2 + w10 * v1 + w11 * v2;
    r.z = w00 * u2 + w01 * u3 + w10 * v2 + w11 * v3;
    r.w = w00 * u3 + w01 * u4 + w10 * v3 + w11 * v4;
    return r;
}

__global__ __launch_bounds__(256) void shift_bilinear_kernel(
    const float* __restrict__ img,
    const float* __restrict__ dxdy,
    float* __restrict__ out)
{
    constexpr int W = 512, H = 512;

    // 256 blocks per image (1024 px per block) -> image index is
    // blockIdx-derived => dxdy load is wave-uniform (s_load).
    const int b  = blockIdx.x >> 8;
    const int lp = ((blockIdx.x & 255) << 10) + ((int)threadIdx.x << 2);
    const int y  = lp >> 9;           // local row
    const int x4 = lp & (W - 1);      // quad start column (multiple of 4)

    const float dy = dxdy[2 * b];
    const float dx = dxdy[2 * b + 1];

    // Per-image constants (uniform across the block).
    const float ny  = -dy,            nx  = -dx;
    const float ayf = floorf(ny),     axf = floorf(nx);
    const float fy  = ny - ayf,       fx  = nx - axf;
    const int   ia  = (int)ayf,       ja  = (int)axf;

    const float gy = 1.0f - fy, gx = 1.0f - fx;
    const float w00 = gy * gx, w01 = gy * fx, w10 = fy * gx, w11 = fy * fx;

    // Source rows (mirror).
    const int r0 = mirror_small(y + ia);
    const int r1 = mirror_small(y + ia + 1);
    const float* __restrict__ R0 = img + (b * H + r0) * W;
    const float* __restrict__ R1 = img + (b * H + r1) * W;

    const int xs   = x4 + ja;        // source column of first tap
    const int base = xs & ~3;        // aligned window start
    // Window offset = ja & 3 (x4 is a multiple of 4) — uniform per block.
    const int osel = __builtin_amdgcn_readfirstlane(ja & 3);

    float4 res;
    if (base >= 0 && base <= W - 8) {
        // Fast path: two aligned float4 loads per source row cover taps
        // xs..xs+4. Lane-contiguous 16 B loads -> ideal coalescing.
        const float4 a0 = *(const float4*)(R0 + base);
        const float4 b0 = *(const float4*)(R0 + base + 4);
        const float4 a1 = *(const float4*)(R1 + base);
        const float4 b1 = *(const float4*)(R1 + base + 4);

        switch (osel) {
        case 0:
            res = blend5(a0.x, a0.y, a0.z, a0.w, b0.x,
                         a1.x, a1.y, a1.z, a1.w, b1.x, w00, w01, w10, w11);
            break;
        case 1:
            res = blend5(a0.y, a0.z, a0.w, b0.x, b0.y,
                         a1.y, a1.z, a1.w, b1.x, b1.y, w00, w01, w10, w11);
            break;
        case 2:
            res = blend5(a0.z, a0.w, b0.x, b0.y, b0.z,
                         a1.z, a1.w, b1.x, b1.y, b1.z, w00, w01, w10, w11);
            break;
        default:
            res = blend5(a0.w, b0.x, b0.y, b0.z, b0.w,
                         a1.w, b1.x, b1.y, b1.z, b1.w, w00, w01, w10, w11);
            break;
        }
    } else {
        // Border quads (~2 per row): per-pixel mirrored scalar gathers.
        float tmp[4];
#pragma unroll
        for (int k = 0; k < 4; ++k) {
            const int c0 = mirror_small(xs + k);
            const int c1 = mirror_small(xs + k + 1);
            tmp[k] = w00 * R0[c0] + w01 * R0[c1]
                   + w10 * R1[c0] + w11 * R1[c1];
        }
        res = make_float4(tmp[0], tmp[1], tmp[2], tmp[3]);
    }

    *(float4*)(out + ((size_t)b << 18) + lp) = res;
}

extern "C" void kernel_launch(void* const* d_in, const int* in_sizes, int n_in,
                              void* d_out, int out_size, void* d_ws, size_t ws_size,
                              hipStream_t stream) {
    const float* images = (const float*)d_in[0];
    const float* dxdy   = (const float*)d_in[1];
    float*       out    = (float*)d_out;

    // out_size = 256*512*512 px; 1024 px per block.
    const int blocks = out_size >> 10;
    shift_bilinear_kernel<<<blocks, 256, 0, stream>>>(images, dxdy, out);
}

// Round 3
// 432.211 us; speedup vs baseline: 1.3599x; 1.0025x over previous
//
#include <hip/hip_runtime.h>

// Bilinear per-image shift with mirror boundary — uniform-shift formulation.
//
// dx,dy constant per image, x,y integer =>
//   floor(x - dx) = x + floor(-dx),  frac(x - dx) = frac(-dx)
// so the op is a per-image constant integer shift + constant 4-tap blend.
//
// R3: 8 px/thread; direct UNALIGNED dwordx4 loads of the tap window
// (gfx950 global loads allow dword-granular misalignment) — eliminates the
// aligned-load + register-select switch entirely.
// Traffic floor: ~196 MB fetch + 256 MB write -> ~72 us @ 6.3 TB/s.

// float4 with 4-byte alignment: lets the compiler emit global_load_dwordx4
// at dword-aligned (not 16B-aligned) addresses.
typedef float f4u __attribute__((ext_vector_type(4), aligned(4)));

__device__ __forceinline__ int mirror_small(int v) {
    // Reflect into [0,511]; valid for v in [-1022, 1533].
    v = abs(v);
    return (v > 511) ? (1022 - v) : v;
}

__global__ __launch_bounds__(256) void shift_bilinear_kernel(
    const float* __restrict__ img,
    const float* __restrict__ dxdy,
    float* __restrict__ out)
{
    constexpr int W = 512, H = 512;

    // 2048 px per block (4 rows), 128 blocks per image -> image index is
    // blockIdx-derived => dxdy load is wave-uniform.
    const int b  = blockIdx.x >> 7;
    const int lp = ((blockIdx.x & 127) << 11) + ((int)threadIdx.x << 3);
    const int y  = lp >> 9;           // local row
    const int x8 = lp & (W - 1);      // 8-px segment start (multiple of 8)

    const float dy = dxdy[2 * b];
    const float dx = dxdy[2 * b + 1];

    // Per-image constants (uniform across the block).
    const float ny  = -dy,        nx  = -dx;
    const float ayf = floorf(ny), axf = floorf(nx);
    const float fy  = ny - ayf,   fx  = nx - axf;
    const int   ia  = (int)ayf,   ja  = (int)axf;

    const float gy = 1.0f - fy, gx = 1.0f - fx;
    const float w00 = gy * gx, w01 = gy * fx, w10 = fy * gx, w11 = fy * fx;

    // Source rows (mirror).
    const int r0 = mirror_small(y + ia);
    const int r1 = mirror_small(y + ia + 1);
    const float* __restrict__ R0 = img + (b * H + r0) * W;
    const float* __restrict__ R1 = img + (b * H + r1) * W;

    const int xs = x8 + ja;           // source column of first tap

    float u[9], v[9];                 // taps xs..xs+8 from the two rows
    if (xs >= 0 && xs <= W - 9) {
        // Fast path: unaligned vector loads (dword-aligned is enough).
        const f4u ua = *(const f4u*)(R0 + xs);
        const f4u ub = *(const f4u*)(R0 + xs + 4);
        const f4u va = *(const f4u*)(R1 + xs);
        const f4u vb = *(const f4u*)(R1 + xs + 4);
        u[0]=ua.x; u[1]=ua.y; u[2]=ua.z; u[3]=ua.w;
        u[4]=ub.x; u[5]=ub.y; u[6]=ub.z; u[7]=ub.w; u[8]=R0[xs + 8];
        v[0]=va.x; v[1]=va.y; v[2]=va.z; v[3]=va.w;
        v[4]=vb.x; v[5]=vb.y; v[6]=vb.z; v[7]=vb.w; v[8]=R1[xs + 8];
    } else {
        // Border segments (first/last thread of a row): mirrored gathers.
#pragma unroll
        for (int k = 0; k < 9; ++k) {
            const int c = mirror_small(xs + k);
            u[k] = R0[c];
            v[k] = R1[c];
        }
    }

    float4 lo, hi;
    lo.x = w00*u[0] + w01*u[1] + w10*v[0] + w11*v[1];
    lo.y = w00*u[1] + w01*u[2] + w10*v[1] + w11*v[2];
    lo.z = w00*u[2] + w01*u[3] + w10*v[2] + w11*v[3];
    lo.w = w00*u[3] + w01*u[4] + w10*v[3] + w11*v[4];
    hi.x = w00*u[4] + w01*u[5] + w10*v[4] + w11*v[5];
    hi.y = w00*u[5] + w01*u[6] + w10*v[5] + w11*v[6];
    hi.z = w00*u[6] + w01*u[7] + w10*v[6] + w11*v[7];
    hi.w = w00*u[7] + w01*u[8] + w10*v[7] + w11*v[8];

    float* o = out + ((size_t)b << 18) + lp;
    *(float4*)(o)     = lo;
    *(float4*)(o + 4) = hi;
}

extern "C" void kernel_launch(void* const* d_in, const int* in_sizes, int n_in,
                              void* d_out, int out_size, void* d_ws, size_t ws_size,
                              hipStream_t stream) {
    const float* images = (const float*)d_in[0];
    const float* dxdy   = (const float*)d_in[1];
    float*       out    = (float*)d_out;

    // out_size = 256*512*512 px; 2048 px per block.
    const int blocks = out_size >> 11;
    shift_bilinear_kernel<<<blocks, 256, 0, stream>>>(images, dxdy, out);
}